// Round 1
// baseline (75.670 us; speedup 1.0000x reference)
//
#include <hip/hip_runtime.h>
#include <hip/hip_bf16.h>

// out[b] = SCALE * dot(x[b], sum_g wsums[g]),  SCALE = 1.5 * 0.5 = 0.75
// x: [1024, 8192] fp32, wsums: [32, 8192] fp32, out: [1024] fp32 (shape [1024,1])

#define K_DIM 8192
#define G_DIM 32
#define SCALE 0.75f

// Kernel A: w_total[k] = sum over 32 groups of wsums[g][k].
// 8192 elems / 4 per thread = 2048 threads = 8 blocks x 256.
__global__ void __launch_bounds__(256) wsum_fold_kernel(
    const float* __restrict__ wsums, float* __restrict__ w_total) {
    const int k = (blockIdx.x * 256 + threadIdx.x) * 4;
    float4 acc = make_float4(0.f, 0.f, 0.f, 0.f);
#pragma unroll
    for (int g = 0; g < G_DIM; ++g) {
        const float4 v = *reinterpret_cast<const float4*>(wsums + (size_t)g * K_DIM + k);
        acc.x += v.x; acc.y += v.y; acc.z += v.z; acc.w += v.w;
    }
    *reinterpret_cast<float4*>(w_total + k) = acc;
}

// Kernel B: one block (256 threads) per row. Each thread reads 8 float4's of x
// (coalesced, 16 B/lane) and the matching w_total chunk (L1/L2-resident, 32 KiB).
__global__ void __launch_bounds__(256) row_dot_kernel(
    const float* __restrict__ x, const float* __restrict__ w_total,
    float* __restrict__ out) {
    const int row = blockIdx.x;
    const float* xr = x + (size_t)row * K_DIM;
    const int t = threadIdx.x;

    float acc = 0.f;
#pragma unroll
    for (int i = 0; i < K_DIM / (256 * 4); ++i) {
        const int k = (i * 256 + t) * 4;
        const float4 xv = *reinterpret_cast<const float4*>(xr + k);
        const float4 wv = *reinterpret_cast<const float4*>(w_total + k);
        acc += xv.x * wv.x + xv.y * wv.y + xv.z * wv.z + xv.w * wv.w;
    }

    // Wave-64 shuffle reduction
#pragma unroll
    for (int off = 32; off > 0; off >>= 1)
        acc += __shfl_down(acc, off, 64);

    __shared__ float smem[4];
    const int lane = t & 63;
    const int wave = t >> 6;
    if (lane == 0) smem[wave] = acc;
    __syncthreads();
    if (t == 0) {
        out[row] = (smem[0] + smem[1] + smem[2] + smem[3]) * SCALE;
    }
}

extern "C" void kernel_launch(void* const* d_in, const int* in_sizes, int n_in,
                              void* d_out, int out_size, void* d_ws, size_t ws_size,
                              hipStream_t stream) {
    const float* x     = (const float*)d_in[0];   // [1024, 8192]
    const float* wsums = (const float*)d_in[1];   // [32, 8192]
    float* out         = (float*)d_out;           // [1024]
    float* w_total     = (float*)d_ws;            // 8192 floats scratch

    const int n_rows = in_sizes[0] / K_DIM;       // 1024

    wsum_fold_kernel<<<K_DIM / (256 * 4), 256, 0, stream>>>(wsums, w_total);
    row_dot_kernel<<<n_rows, 256, 0, stream>>>(x, w_total, out);
}